// Round 6
// baseline (8622.874 us; speedup 1.0000x reference)
//
#include <hip/hip_runtime.h>
#include <hip/hip_bf16.h>

// LSTM: B=64, T=512, I=256, H=1024, O=1.
// Persistent cooperative kernel: 256 blocks = 4 batch-groups x 64 unit-groups.
// R6: tagged-h dataflow. h stored as dword (tag<<16 | bf16), tag = step.
// Producer: fire-and-forget tagged stores (NO drain, NO flag). Consumer:
// polls the exact dwords it feeds to MFMA until all tags match — detect and
// data arrive in the same load (~1 LLC RT instead of ~4). R4 wave0 epilogue,
// double-buffered red LDS, one __syncthreads per step.

typedef __bf16 bf16_t;
typedef bf16_t b16x8 __attribute__((ext_vector_type(8)));
typedef float  f32x4 __attribute__((ext_vector_type(4)));

#define TQ 512
#define IQ 256
#define HQ 1024

union U8 { b16x8 b; unsigned short u[8]; };

__device__ __forceinline__ float bf2f(unsigned short s) {
    return __uint_as_float(((unsigned)s) << 16);
}
__device__ __forceinline__ unsigned short f2bf(float f) {
    unsigned u = __float_as_uint(f);
    u += 0x7fff + ((u >> 16) & 1);   // RNE
    return (unsigned short)(u >> 16);
}
__device__ __forceinline__ b16x8 cvt84(float4 a, float4 b) {
    U8 r;
    r.u[0] = f2bf(a.x); r.u[1] = f2bf(a.y); r.u[2] = f2bf(a.z); r.u[3] = f2bf(a.w);
    r.u[4] = f2bf(b.x); r.u[5] = f2bf(b.y); r.u[6] = f2bf(b.z); r.u[7] = f2bf(b.w);
    return r.b;
}
__device__ __forceinline__ unsigned long long ld8(const unsigned* p) {
    return __hip_atomic_load((const unsigned long long*)p,
                             __ATOMIC_RELAXED, __HIP_MEMORY_SCOPE_AGENT);
}
__device__ __forceinline__ unsigned ld4(const unsigned* p) {
    return __hip_atomic_load(p, __ATOMIC_RELAXED, __HIP_MEMORY_SCOPE_AGENT);
}
__device__ __forceinline__ float sigm(float x) {
    return 1.f / (1.f + __expf(-x));
}
__device__ __forceinline__ float tanh_f(float v) {
    float x = fminf(fmaxf(v, -15.f), 15.f);
    float e = __expf(2.f * x);
    return (e - 1.f) / (e + 1.f);
}

__launch_bounds__(512, 2)
__global__ void lstm_persist(const float* __restrict__ x,
                             const float* __restrict__ Wih,
                             const float* __restrict__ Whh,
                             const float* __restrict__ bih,
                             const float* __restrict__ bhh,
                             const float* __restrict__ fcW,
                             const float* __restrict__ fcb,
                             float* __restrict__ out,
                             unsigned* __restrict__ hbuf)   // [2][4][16][1024] dwords
{
    __shared__ float red[2 * 8192];   // 64KB: double-buffered per-wave partials

    const int tid  = threadIdx.x;
    const int w    = tid >> 6;        // wave 0..7
    const int lane = tid & 63;
    const int bid  = blockIdx.x;
    const int bg   = bid & 3;         // batch group (16 batches)
    const int ug   = bid >> 2;        // unit group (16 hidden units)

    const int l16  = lane & 15;
    const int quad = lane >> 4;

    // ---- one-time: load weight fragments into registers (bf16) ----
    // B^T-fragment: lane holds W[row = base + l16][k0 + quad*8 + j]
    b16x8 wih[4];        // x part: this wave's x-kstep
    b16x8 whh[4][4];     // h part: 4 ksteps x 4 gates
    {
        const int koff = quad * 8;
        #pragma unroll
        for (int g = 0; g < 4; ++g) {
            int row = g * HQ + ug * 16 + l16;
            const float* p = Wih + (size_t)row * IQ + w * 32 + koff;
            float4 a = *(const float4*)p;
            float4 b = *(const float4*)(p + 4);
            wih[g] = cvt84(a, b);
            #pragma unroll
            for (int j = 0; j < 4; ++j) {
                int k0 = (w * 4 + j) * 32 + koff;
                const float* q = Whh + (size_t)row * HQ + k0;
                float4 c = *(const float4*)q;
                float4 d = *(const float4*)(q + 4);
                whh[j][g] = cvt84(c, d);
            }
        }
    }

    // wave0 epilogue state: lane owns (u = l16, batches quad*4 + r)
    float c_st[4] = {0.f, 0.f, 0.f, 0.f};
    float bias_r[4];
    if (w == 0) {
        #pragma unroll
        for (int g = 0; g < 4; ++g) {
            int gr = g * HQ + ug * 16 + l16;
            bias_r[g] = bih[gr] + bhh[gr];
        }
    }

    // this lane's h dwords: batch row l16, units (w*4+j)*32 + quad*8 .. +7
    const int ubase = w * 128 + quad * 8;   // + j*32

    // software-pipelined x load (step 0)
    const float* xbase = x + ((size_t)(bg * 16 + l16) * TQ) * IQ + w * 32 + quad * 8;
    float4 xa = *(const float4*)(xbase);
    float4 xb = *(const float4*)(xbase + 4);

    for (int t = 0; t < TQ; ++t) {
        const int p = t & 1;

        // ---- h-independent shadow work ----
        b16x8 ax = cvt84(xa, xb);
        f32x4 acc[4];
        #pragma unroll
        for (int g = 0; g < 4; ++g) {
            f32x4 z = {0.f, 0.f, 0.f, 0.f};
            acc[g] = __builtin_amdgcn_mfma_f32_16x16x32_bf16(ax, wih[g], z, 0, 0, 0);
        }

        // ---- tagged-h poll: load the exact dwords we consume ----
        const unsigned* hrow = hbuf + (((size_t)p * 4 + bg) * 16 + l16) * HQ;
        unsigned long long v[16];
        {
            const unsigned tt = (unsigned)t;
            int spins = 0;
            for (;;) {
                #pragma unroll
                for (int j = 0; j < 4; ++j) {
                    const unsigned* pj = hrow + ubase + j * 32;
                    #pragma unroll
                    for (int k = 0; k < 4; ++k)
                        v[j * 4 + k] = ld8(pj + k * 2);
                }
                bool ok = true;
                #pragma unroll
                for (int i = 0; i < 16; ++i) {
                    ok = ok && (((unsigned)(v[i] >> 16) & 0xffffu) == tt)
                            && (((unsigned)(v[i] >> 48)) == tt);
                }
                if (__all(ok)) break;
                if (++spins > 4) __builtin_amdgcn_s_sleep(1);
            }
        }

        // ---- unpack low16s into A-fragments + h MFMAs ----
        b16x8 ah[4];
        #pragma unroll
        for (int j = 0; j < 4; ++j) {
            U8 tmp;
            #pragma unroll
            for (int k = 0; k < 4; ++k) {
                unsigned long long q = v[j * 4 + k];
                tmp.u[2 * k]     = (unsigned short)(q & 0xffffu);
                tmp.u[2 * k + 1] = (unsigned short)((q >> 32) & 0xffffu);
            }
            ah[j] = tmp.b;
        }
        #pragma unroll
        for (int j = 0; j < 4; ++j) {
            #pragma unroll
            for (int g = 0; g < 4; ++g)
                acc[g] = __builtin_amdgcn_mfma_f32_16x16x32_bf16(ah[j], whh[j][g], acc[g], 0, 0, 0);
        }

        // ---- write per-wave partials (double-buffered) ----
        float* rb = &red[p * 8192];
        #pragma unroll
        for (int g = 0; g < 4; ++g)
            *(f32x4*)&rb[((w * 4 + g) * 64 + lane) * 4] = acc[g];
        __syncthreads();   // the single per-step block barrier

        if (w == 0) {
            // ---- reduce 8 K-partials ----
            f32x4 gv[4];
            #pragma unroll
            for (int g = 0; g < 4; ++g) {
                f32x4 s = *(const f32x4*)&rb[((0 * 4 + g) * 64 + lane) * 4];
                #pragma unroll
                for (int ww = 1; ww < 8; ++ww)
                    s += *(const f32x4*)&rb[((ww * 4 + g) * 64 + lane) * 4];
                gv[g] = s;
            }
            // ---- nonlinearities + tagged h stores (fire-and-forget) ----
            unsigned* hw = hbuf + ((size_t)(p ^ 1) * 4 + bg) * (16 * HQ)
                         + (size_t)ug * 16 + l16;
            const unsigned tagv = ((unsigned)(t + 1)) << 16;
            #pragma unroll
            for (int r = 0; r < 4; ++r) {
                float gi = gv[0][r] + bias_r[0];
                float gf = gv[1][r] + bias_r[1];
                float gg = gv[2][r] + bias_r[2];
                float go = gv[3][r] + bias_r[3];
                float i_s = sigm(gi);
                float f_s = sigm(gf);
                float g_t = tanh_f(gg);
                float o_s = sigm(go);
                float c = f_s * c_st[r] + i_s * g_t;
                c_st[r] = c;
                float h = o_s * tanh_f(c);
                int b = quad * 4 + r;
                __hip_atomic_store(hw + (size_t)b * HQ, tagv | (unsigned)f2bf(h),
                                   __ATOMIC_RELAXED, __HIP_MEMORY_SCOPE_AGENT);
            }
        }
        // x prefetch t+1 (all waves; no drain to protect anymore)
        {
            size_t nt = (t + 1 < TQ) ? (size_t)(t + 1) * IQ : (size_t)t * IQ;
            xa = *(const float4*)(xbase + nt);
            xb = *(const float4*)(xbase + nt + 4);
        }
    }

    // ---- final projection: out = tanh(h_T) @ fcW^T + fcb (blocks 0..3) ----
    if (bid < 4) {
        const unsigned* hl = hbuf + (size_t)bg * (16 * HQ); // T even -> parity 0
        const unsigned ft = (unsigned)TQ;
        float fb = fcb[0];
        #pragma unroll
        for (int r = 0; r < 2; ++r) {
            int b = w * 2 + r;
            float s = 0.f;
            #pragma unroll
            for (int j = 0; j < 16; ++j) {
                int u = j * 64 + lane;
                unsigned hv = ld4(hl + (size_t)b * HQ + u);
                while ((hv >> 16) != ft) hv = ld4(hl + (size_t)b * HQ + u);
                s += tanh_f(bf2f((unsigned short)(hv & 0xffffu))) * fcW[u];
            }
            #pragma unroll
            for (int off = 32; off > 0; off >>= 1)
                s += __shfl_down(s, off);
            if (lane == 0) out[bg * 16 + b] = s + fb;
        }
    }
}

extern "C" void kernel_launch(void* const* d_in, const int* in_sizes, int n_in,
                              void* d_out, int out_size, void* d_ws, size_t ws_size,
                              hipStream_t stream) {
    (void)in_sizes; (void)n_in; (void)out_size; (void)ws_size;
    const float* x   = (const float*)d_in[0];
    const float* Wih = (const float*)d_in[1];
    const float* Whh = (const float*)d_in[2];
    const float* bih = (const float*)d_in[3];
    const float* bhh = (const float*)d_in[4];
    const float* fcW = (const float*)d_in[5];
    const float* fcb = (const float*)d_in[6];
    float* out = (float*)d_out;

    unsigned* hbuf = (unsigned*)d_ws;   // [2][4][16][1024] dwords = 524288 B

    // zero h buffers: tag 0 == "h(0)=0 is ready" (ws poisoned 0xAA each launch)
    hipMemsetAsync(d_ws, 0, 524288, stream);

    void* args[] = { &x, &Wih, &Whh, &bih, &bhh, &fcW, &fcb, &out, &hbuf };
    hipLaunchCooperativeKernel(reinterpret_cast<void*>(lstm_persist),
                               dim3(256), dim3(512), args, 0, stream);
}

// Round 7
// 2418.745 us; speedup vs baseline: 3.5650x; 3.5650x over previous
//
#include <hip/hip_runtime.h>
#include <hip/hip_bf16.h>

// LSTM: B=64, T=512, I=256, H=1024, O=1.
// Persistent cooperative kernel: 256 blocks = 4 batch-groups x 64 unit-groups.
// R7 = R4 + per-kstep dependency pipelining: each kstep j of a wave's K-slice
// depends on exactly 2 producer blocks; poll those 2 flags, immediately issue
// the 16B h-load for j, then poll kstep j+1 — loads overlap later detects,
// MFMAs overlap tail loads. Flags only are polled (tiny footprint, R6 lesson).
// Producer: R4's wave0 epilogue (reduce + nonlin + h store + vmcnt drain +
// flag store). One __syncthreads per step, double-buffered partial LDS.

typedef __bf16 bf16_t;
typedef bf16_t b16x8 __attribute__((ext_vector_type(8)));
typedef float  f32x4 __attribute__((ext_vector_type(4)));

#define TQ 512
#define IQ 256
#define HQ 1024

union U8 { b16x8 b; unsigned long long q[2]; unsigned short u[8]; };

__device__ __forceinline__ float bf2f(unsigned short s) {
    return __uint_as_float(((unsigned)s) << 16);
}
__device__ __forceinline__ unsigned short f2bf(float f) {
    unsigned u = __float_as_uint(f);
    u += 0x7fff + ((u >> 16) & 1);   // RNE
    return (unsigned short)(u >> 16);
}
__device__ __forceinline__ b16x8 cvt84(float4 a, float4 b) {
    U8 r;
    r.u[0] = f2bf(a.x); r.u[1] = f2bf(a.y); r.u[2] = f2bf(a.z); r.u[3] = f2bf(a.w);
    r.u[4] = f2bf(b.x); r.u[5] = f2bf(b.y); r.u[6] = f2bf(b.z); r.u[7] = f2bf(b.w);
    return r.b;
}
// agent-scope 16B load as 2x8B atomic loads — bypasses non-coherent L1/L2
__device__ __forceinline__ b16x8 load_h16(const unsigned short* p) {
    U8 r;
    r.q[0] = __hip_atomic_load((const unsigned long long*)p,
                               __ATOMIC_RELAXED, __HIP_MEMORY_SCOPE_AGENT);
    r.q[1] = __hip_atomic_load((const unsigned long long*)(p + 4),
                               __ATOMIC_RELAXED, __HIP_MEMORY_SCOPE_AGENT);
    return r.b;
}
__device__ __forceinline__ unsigned ld_flag(const unsigned int* p) {
    return __hip_atomic_load(p, __ATOMIC_RELAXED, __HIP_MEMORY_SCOPE_AGENT);
}
__device__ __forceinline__ float sigm(float x) {
    return 1.f / (1.f + __expf(-x));
}
__device__ __forceinline__ float tanh_f(float v) {
    float x = fminf(fmaxf(v, -15.f), 15.f);
    float e = __expf(2.f * x);
    return (e - 1.f) / (e + 1.f);
}

__launch_bounds__(512, 2)
__global__ void lstm_persist(const float* __restrict__ x,
                             const float* __restrict__ Wih,
                             const float* __restrict__ Whh,
                             const float* __restrict__ bih,
                             const float* __restrict__ bhh,
                             const float* __restrict__ fcW,
                             const float* __restrict__ fcb,
                             float* __restrict__ out,
                             unsigned short* __restrict__ hbuf, // [2][4][16][1024] bf16
                             unsigned int* __restrict__ bar)    // [4][64] flags, 64B apart
{
    __shared__ float red[2 * 8192];   // 64KB: double-buffered per-wave partials

    const int tid  = threadIdx.x;
    const int w    = tid >> 6;        // wave 0..7
    const int lane = tid & 63;
    const int bid  = blockIdx.x;
    const int bg   = bid & 3;         // batch group (16 batches)
    const int ug   = bid >> 2;        // unit group (16 hidden units)

    const int l16  = lane & 15;
    const int quad = lane >> 4;

    // ---- one-time: load weight fragments into registers (bf16) ----
    // B^T-fragment: lane holds W[row = base + l16][k0 + quad*8 + j]
    b16x8 wih[4];        // x part: this wave's x-kstep
    b16x8 whh[4][4];     // h part: 4 ksteps x 4 gates
    {
        const int koff = quad * 8;
        #pragma unroll
        for (int g = 0; g < 4; ++g) {
            int row = g * HQ + ug * 16 + l16;
            const float* p = Wih + (size_t)row * IQ + w * 32 + koff;
            float4 a = *(const float4*)p;
            float4 b = *(const float4*)(p + 4);
            wih[g] = cvt84(a, b);
            #pragma unroll
            for (int j = 0; j < 4; ++j) {
                int k0 = (w * 4 + j) * 32 + koff;
                const float* q = Whh + (size_t)row * HQ + k0;
                float4 c = *(const float4*)q;
                float4 d = *(const float4*)(q + 4);
                whh[j][g] = cvt84(c, d);
            }
        }
    }

    // wave0 epilogue state: lane owns (u = l16, batches quad*4 + r)
    float c_st[4] = {0.f, 0.f, 0.f, 0.f};
    float bias_r[4];
    if (w == 0) {
        #pragma unroll
        for (int g = 0; g < 4; ++g) {
            int gr = g * HQ + ug * 16 + l16;
            bias_r[g] = bih[gr] + bhh[gr];
        }
    }

    // flags for this batch group: fl[j*16] is producer j's step counter
    unsigned int* fl = bar + (size_t)bg * 1024;           // 64 x 64B
    // per-kstep flag pointers: kstep j needs producers 2*(4w+j), 2*(4w+j)+1
    const unsigned int* flj[4];
    #pragma unroll
    for (int j = 0; j < 4; ++j)
        flj[j] = fl + (size_t)((w * 4 + j) * 2 + (lane & 1)) * 16;
    // full-coverage pointer for the final wait (8 producers across lanes)
    const unsigned int* myfl = fl + (size_t)(w * 8 + (lane & 7)) * 16;

    // software-pipelined x load (step 0)
    const float* xbase = x + ((size_t)(bg * 16 + l16) * TQ) * IQ + w * 32 + quad * 8;
    float4 xa = *(const float4*)(xbase);
    float4 xb = *(const float4*)(xbase + 4);

    for (int t = 0; t < TQ; ++t) {
        const int p = t & 1;

        // ---- h-independent shadow work ----
        b16x8 ax = cvt84(xa, xb);
        f32x4 acc[4];
        #pragma unroll
        for (int g = 0; g < 4; ++g) {
            f32x4 z = {0.f, 0.f, 0.f, 0.f};
            acc[g] = __builtin_amdgcn_mfma_f32_16x16x32_bf16(ax, wih[g], z, 0, 0, 0);
        }

        // ---- per-kstep wait + overlapped h loads ----
        const unsigned short* hread = hbuf + ((size_t)p * 4 + bg) * (16 * HQ);
        b16x8 ah[4];
        #pragma unroll
        for (int j = 0; j < 4; ++j) {
            if (t) {
                // 2-deep pipelined poll on the 2 producers of kstep j
                unsigned va = ld_flag(flj[j]);
                unsigned vb = ld_flag(flj[j]);
                for (;;) {
                    if (__all((int)va >= t)) break;
                    va = ld_flag(flj[j]);
                    if (__all((int)vb >= t)) break;
                    vb = ld_flag(flj[j]);
                }
            }
            // issue the h load for kstep j; value used later (deferred vmcnt)
            ah[j] = load_h16(hread + (size_t)l16 * HQ + (w * 4 + j) * 32 + quad * 8);
        }

        // ---- h MFMAs (start as soon as ah[0] lands; tail loads overlap) ----
        #pragma unroll
        for (int j = 0; j < 4; ++j) {
            #pragma unroll
            for (int g = 0; g < 4; ++g)
                acc[g] = __builtin_amdgcn_mfma_f32_16x16x32_bf16(ah[j], whh[j][g], acc[g], 0, 0, 0);
        }

        // ---- write per-wave partials (double-buffered) ----
        float* rb = &red[p * 8192];
        #pragma unroll
        for (int g = 0; g < 4; ++g)
            *(f32x4*)&rb[((w * 4 + g) * 64 + lane) * 4] = acc[g];
        __syncthreads();   // the single per-step block barrier

        if (w == 0) {
            // ---- reduce 8 K-partials ----
            f32x4 gv[4];
            #pragma unroll
            for (int g = 0; g < 4; ++g) {
                f32x4 s = *(const f32x4*)&rb[((0 * 4 + g) * 64 + lane) * 4];
                #pragma unroll
                for (int ww = 1; ww < 8; ++ww)
                    s += *(const f32x4*)&rb[((ww * 4 + g) * 64 + lane) * 4];
                gv[g] = s;
            }
            // ---- nonlinearities + h stores, interleaved per batch row ----
            unsigned short* hw = hbuf + ((size_t)(p ^ 1) * 4 + bg) * (16 * HQ)
                               + (size_t)ug * 16 + l16;
            #pragma unroll
            for (int r = 0; r < 4; ++r) {
                float gi = gv[0][r] + bias_r[0];
                float gf = gv[1][r] + bias_r[1];
                float gg = gv[2][r] + bias_r[2];
                float go = gv[3][r] + bias_r[3];
                float i_s = sigm(gi);
                float f_s = sigm(gf);
                float g_t = tanh_f(gg);
                float o_s = sigm(go);
                float c = f_s * c_st[r] + i_s * g_t;
                c_st[r] = c;
                float h = o_s * tanh_f(c);
                int b = quad * 4 + r;
                __hip_atomic_store(hw + (size_t)b * HQ, f2bf(h),
                                   __ATOMIC_RELAXED, __HIP_MEMORY_SCOPE_AGENT);
            }
            // drain h stores to the device-visible point, then signal
            asm volatile("s_waitcnt vmcnt(0)" ::: "memory");
            if (lane == 0)
                __hip_atomic_store(fl + (size_t)ug * 16, (unsigned)(t + 1),
                                   __ATOMIC_RELAXED, __HIP_MEMORY_SCOPE_AGENT);
            asm volatile("" ::: "memory");   // keep x prefetch out of the drain
            size_t nt = (t + 1 < TQ) ? (size_t)(t + 1) * IQ : (size_t)t * IQ;
            xa = *(const float4*)(xbase + nt);
            xb = *(const float4*)(xbase + nt + 4);
        } else {
            // x prefetch overlaps wave0's epilogue
            size_t nt = (t + 1 < TQ) ? (size_t)(t + 1) * IQ : (size_t)t * IQ;
            xa = *(const float4*)(xbase + nt);
            xb = *(const float4*)(xbase + nt + 4);
        }
    }

    // ---- final projection: out = tanh(h_T) @ fcW^T + fcb (blocks 0..3) ----
    if (bid < 4) {
        {   // all 8 waves collectively verify all 64 producers finished
            unsigned va = ld_flag(myfl);
            while (!__all((int)va >= TQ))
                va = ld_flag(myfl);
        }
        __syncthreads();
        const unsigned short* hl = hbuf + (size_t)bg * (16 * HQ); // T even -> buf0
        float fb = fcb[0];
        #pragma unroll
        for (int r = 0; r < 2; ++r) {
            int b = w * 2 + r;
            float s = 0.f;
            #pragma unroll
            for (int j = 0; j < 16; ++j) {
                int u = j * 64 + lane;
                unsigned short hv = __hip_atomic_load(hl + b * HQ + u,
                                                      __ATOMIC_RELAXED,
                                                      __HIP_MEMORY_SCOPE_AGENT);
                s += tanh_f(bf2f(hv)) * fcW[u];
            }
            #pragma unroll
            for (int off = 32; off > 0; off >>= 1)
                s += __shfl_down(s, off);
            if (lane == 0) out[bg * 16 + b] = s + fb;
        }
    }
}

extern "C" void kernel_launch(void* const* d_in, const int* in_sizes, int n_in,
                              void* d_out, int out_size, void* d_ws, size_t ws_size,
                              hipStream_t stream) {
    (void)in_sizes; (void)n_in; (void)out_size; (void)ws_size;
    const float* x   = (const float*)d_in[0];
    const float* Wih = (const float*)d_in[1];
    const float* Whh = (const float*)d_in[2];
    const float* bih = (const float*)d_in[3];
    const float* bhh = (const float*)d_in[4];
    const float* fcW = (const float*)d_in[5];
    const float* fcb = (const float*)d_in[6];
    float* out = (float*)d_out;

    unsigned short* hbuf = (unsigned short*)d_ws;                       // 262144 B
    unsigned int*   bar  = (unsigned int*)((char*)d_ws + 262144);       // 16384 B

    hipMemsetAsync(d_ws, 0, 262144 + 16384, stream);

    void* args[] = { &x, &Wih, &Whh, &bih, &bhh, &fcW, &fcb, &out, &hbuf, &bar };
    hipLaunchCooperativeKernel(reinterpret_cast<void*>(lstm_persist),
                               dim3(256), dim3(512), args, 0, stream);
}